// Round 1
// 297.079 us; speedup vs baseline: 1.0691x; 1.0691x over previous
//
#include <hip/hip_runtime.h>
#include <math.h>

#define NB 8
#define NC 192
#define NH 56
#define NW 56
#define NN 3136      // NH*NW
#define NK 16        // clusters
#define KNB 9        // neighbors
#define NCOUT 384    // 2*NC
#define LPMAX 320    // max padded cluster size (L~196±14, 320 is >8 sigma)
#define DSTRIDE 320
#define DSLOT (320 * 320)

#define FLT_INF __builtin_inff()

typedef short s16x8 __attribute__((ext_vector_type(8)));
typedef _Float16 f16x8 __attribute__((ext_vector_type(8)));
typedef float f32x4 __attribute__((ext_vector_type(4)));
typedef unsigned short us8 __attribute__((ext_vector_type(8)));
typedef unsigned short us4 __attribute__((ext_vector_type(4)));

// gelu(tanh approx) via exact sigmoid identity: 0.5*(1+tanh(u)) = 1/(1+exp(-2u)).
// One v_exp + one v_rcp instead of libm tanhf (~30 instrs). exp(+inf)->inf, rcp(inf)->0: stable.
__device__ __forceinline__ float gelu_t(float x) {
    const float k0 = 0.7978845608028654f;
    float u = k0 * (x + 0.044715f * x * x * x);
    float sg = __builtin_amdgcn_rcpf(1.0f + __expf(-2.0f * u));
    return x * sg;
}

__device__ __forceinline__ unsigned short f2bf(float f) {
    unsigned u = __float_as_uint(f);
    u += 0x7fff + ((u >> 16) & 1);  // round-to-nearest-even
    return (unsigned short)(u >> 16);
}

__device__ __forceinline__ float bf2f(unsigned short h) {
    return __uint_as_float(((unsigned)h) << 16);
}

// ---------------- fused front kernel: conv (blocks 0..1535) | order (1536..1663) | wcvt (1664..1951)
// All three are independent; fusing hides order_kernel's latency-bound 128x64 dispatch
// under conv's 1536 compute blocks and drops two launch gaps.
#define FRONT_CONV_BLOCKS (NB * NC)            // 1536
#define FRONT_ORDER_BLOCKS (NB * NK)           // 128
#define FRONT_WCVT_BLOCKS 288                  // 6*12*4
__global__ __launch_bounds__(256) void front_kernel(
    const float* __restrict__ X, const float* __restrict__ W7, const float* __restrict__ bias,
    unsigned short* __restrict__ xpe,
    const int* __restrict__ labels, int* __restrict__ order, int* __restrict__ mapping,
    int* __restrict__ lsv, int* __restrict__ cntk, int* __restrict__ offk,
    const float* __restrict__ Wf1, const float* __restrict__ Wv, const float* __restrict__ Wf2,
    unsigned short* __restrict__ wf1, unsigned short* __restrict__ wfpmq,
    unsigned short* __restrict__ wfq, unsigned short* __restrict__ wf2) {
    __shared__ float tile[62 * 62];
    __shared__ float wl[49];
    int bid = blockIdx.x;
    int tid = threadIdx.x;
    if (bid < FRONT_CONV_BLOCKS) {
        // -------- depthwise 7x7 conv + bias + residual -> bf16 xpe --------
        int bc = bid;
        int c = bc % NC;
        const float* Xp = X + (size_t)bc * NN;
        if (tid < 49) wl[tid] = W7[(size_t)c * 49 + tid];
        for (int idx = tid; idx < 62 * 62; idx += 256) {
            int ty = idx / 62, tx = idx % 62;
            int gy = ty - 3, gx = tx - 3;
            float v = 0.0f;
            if (gy >= 0 && gy < NH && gx >= 0 && gx < NW) v = Xp[gy * NW + gx];
            tile[idx] = v;
        }
        __syncthreads();
        float cb = bias[c];
        for (int g = tid; g < (NN / 4); g += 256) {
            int y = g / (NW / 4), x0 = (g % (NW / 4)) * 4;
            float a0 = 0.f, a1 = 0.f, a2 = 0.f, a3 = 0.f;
#pragma unroll
            for (int dy = 0; dy < 7; ++dy) {
                const float* tr = &tile[(y + dy) * 62 + x0];
#pragma unroll
                for (int dx = 0; dx < 7; ++dx) {
                    float wv = wl[dy * 7 + dx];
                    a0 += tr[dx] * wv;
                    a1 += tr[dx + 1] * wv;
                    a2 += tr[dx + 2] * wv;
                    a3 += tr[dx + 3] * wv;
                }
            }
            const float* rr = &tile[(y + 3) * 62 + x0 + 3];
            us4 o;
            o[0] = f2bf(a0 + cb + rr[0]);
            o[1] = f2bf(a1 + cb + rr[1]);
            o[2] = f2bf(a2 + cb + rr[2]);
            o[3] = f2bf(a3 + cb + rr[3]);
            *(us4*)(xpe + (size_t)bc * NN + y * NW + x0) = o;
        }
    } else if (bid < FRONT_CONV_BLOCKS + FRONT_ORDER_BLOCKS) {
        // -------- stable counting sort (wave 0 only; identical logic to standalone) --------
        if (tid >= 64) return;
        int idx = bid - FRONT_CONV_BLOCKS;
        int b = idx >> 4;
        int k = idx & 15;
        int lane = tid;
        const int* lb = labels + (size_t)b * NN;
        int cntLess = 0, cntEq = 0;
        for (int n0 = 0; n0 < NN; n0 += 64) {
            int lab = lb[n0 + lane] & 15;
            cntLess += __popcll(__ballot(lab < k));
            cntEq += __popcll(__ballot(lab == k));
        }
        int base = cntLess;
        int run = 0;
        for (int n0 = 0; n0 < NN; n0 += 64) {
            int n = n0 + lane;
            int lab = lb[n] & 15;
            bool p = (lab == k);
            unsigned long long mask = __ballot(p);
            int rank = __popcll(mask & ((1ull << lane) - 1ull));
            if (p) {
                int pos = base + run + rank;
                order[b * NN + pos] = n;
                mapping[b * NN + n] = pos;
                lsv[b * NN + pos] = k;
            }
            run += __popcll(mask);
        }
        if (lane == 0) {
            offk[b * NK + k] = base;
            cntk[b * NK + k] = cntEq;
        }
    } else {
        // -------- weight -> B-fragment conversions --------
        int u = bid - (FRONT_CONV_BLOCKS + FRONT_ORDER_BLOCKS);
        int nt = u % 6, kc = (u / 6) % 12, z = u / 72;
        const float* W;
        unsigned short* Bf;
        int ldw, rowoff, KC, NT;
        bool diff = false;
        if (z == 0) { W = Wf1; Bf = wf1; ldw = NC; rowoff = 0; KC = 6; NT = 3; }
        else if (z == 1) { W = Wv; Bf = wfpmq; ldw = NCOUT; rowoff = 0; KC = 6; NT = 6; diff = true; }
        else if (z == 2) { W = Wv; Bf = wfq; ldw = NCOUT; rowoff = NC; KC = 6; NT = 6; }
        else { W = Wf2; Bf = wf2; ldw = NC; rowoff = 0; KC = 12; NT = 3; }
        if (nt >= NT || kc >= KC) return;
        int c = tid >> 6, l = tid & 63;
        int n = l & 15, q = l >> 4;
        int col = nt * 64 + c * 16 + n;
        int krow = rowoff + kc * 32 + q * 8;
        unsigned short pack[8];
#pragma unroll
        for (int j = 0; j < 8; ++j) {
            float v = W[(size_t)(krow + j) * ldw + col];
            if (diff) v -= W[(size_t)(NC + krow + j) * ldw + col];
            pack[j] = f2bf(v);
        }
        *(us8*)(Bf + ((((size_t)nt * KC + kc) * 4 + c) * 64 + l) * 8) = *(const us8*)pack;
    }
}

// ---------------- bf16 xpe [b][c][n] -> A-fragment for fc1 (pure repack) ----------------
__global__ __launch_bounds__(256) void tcvt_kernel(const unsigned short* __restrict__ xpe,
                                                   unsigned short* __restrict__ Af) {
    __shared__ unsigned short t[32][72];
    int b = blockIdx.z, kc = blockIdx.y, n0 = blockIdx.x * 64;
    int tid = threadIdx.x;
    int cl = tid >> 3, nl = (tid & 7) * 8;
    const unsigned short* src = xpe + ((size_t)b * NC + kc * 32 + cl) * NN + n0 + nl;
    *(us8*)&t[cl][nl] = *(const us8*)src;
    __syncthreads();
    int w = tid >> 6, l = tid & 63;
    int m = l & 15, q = l >> 4;
    int nloc = w * 16 + m;
    unsigned short pack[8];
#pragma unroll
    for (int j = 0; j < 8; ++j) pack[j] = t[q * 8 + j][nloc];
    int sg = blockIdx.x * 4 + w;
    *(us8*)(Af + (size_t)b * NN * NC + (((size_t)sg * 6 + kc) * 64 + l) * 8) =
        *(const us8*)pack;
}

// ---------------- LDS-free MFMA GEMM: fragment-streaming, fp32 out (+opt scatter/frag) ----------------
template <int KC>
__global__ __launch_bounds__(256) void gemm_mfma(const unsigned short* __restrict__ Af,
                                                 size_t aStride,
                                                 const unsigned short* __restrict__ Bf,
                                                 const float* __restrict__ bias,
                                                 float* __restrict__ C, size_t cStride,
                                                 int ldc, unsigned short* __restrict__ Cfrag,
                                                 const int* __restrict__ rowmap) {
    int b = blockIdx.z;
    int w = threadIdx.x >> 6, lane = threadIdx.x & 63;
    int sg = blockIdx.y * 4 + w;
    int n0 = blockIdx.x * 64;
    const unsigned short* Ap = Af + (size_t)b * aStride + ((size_t)sg * KC * 64 + lane) * 8;
    const unsigned short* Bp = Bf + ((size_t)blockIdx.x * KC * 256 + lane) * 8;
    f32x4 acc[4] = {};
#pragma unroll
    for (int kc = 0; kc < KC; ++kc) {
        s16x8 a = *(const s16x8*)(Ap + kc * 512);
#pragma unroll
        for (int c = 0; c < 4; ++c) {
            s16x8 bv = *(const s16x8*)(Bp + kc * 2048 + c * 512);
            acc[c] = __builtin_amdgcn_mfma_f32_16x16x32_bf16(a, bv, acc[c], 0, 0, 0);
        }
    }
    int col0 = lane & 15, rq = lane >> 4;
    float* Cb = C + (size_t)b * cStride;
    int kcd = ldc >> 5;
#pragma unroll
    for (int r = 0; r < 4; ++r) {
        int grow = sg * 16 + rq * 4 + r;
        int orow = rowmap ? rowmap[(size_t)b * NN + grow] : grow;
#pragma unroll
        for (int c = 0; c < 4; ++c) {
            int col = n0 + c * 16 + col0;
            float v = acc[c][r];
            if (bias) v += bias[col];
            Cb[(size_t)orow * ldc + col] = v;
            if (Cfrag) {
                int s2 = orow >> 4, m2 = orow & 15;
                int kc2 = col >> 5, q2 = (col >> 3) & 3, j2 = col & 7;
                Cfrag[(size_t)b * cStride +
                      (((size_t)s2 * kcd + kc2) * 64 + q2 * 16 + m2) * 8 + j2] = f2bf(v);
            }
        }
    }
}

// ---------------- merged P/Q GEMM: one A pass, two bf16 outputs ----------------
template <int KC>
__global__ __launch_bounds__(256) void gemm_mfma_pq(const unsigned short* __restrict__ Af,
                                                    size_t aStride,
                                                    const unsigned short* __restrict__ B1,
                                                    const unsigned short* __restrict__ B2,
                                                    const float* __restrict__ bias,
                                                    unsigned short* __restrict__ PmQ,
                                                    unsigned short* __restrict__ Qh,
                                                    size_t cStride, int ldc) {
    int b = blockIdx.z;
    int w = threadIdx.x >> 6, lane = threadIdx.x & 63;
    int sg = blockIdx.y * 4 + w;
    int n0 = blockIdx.x * 64;
    const unsigned short* Ap = Af + (size_t)b * aStride + ((size_t)sg * KC * 64 + lane) * 8;
    const unsigned short* Bp1 = B1 + ((size_t)blockIdx.x * KC * 256 + lane) * 8;
    const unsigned short* Bp2 = B2 + ((size_t)blockIdx.x * KC * 256 + lane) * 8;
    f32x4 acc1[4] = {};
    f32x4 acc2[4] = {};
#pragma unroll
    for (int kc = 0; kc < KC; ++kc) {
        s16x8 a = *(const s16x8*)(Ap + kc * 512);
#pragma unroll
        for (int c = 0; c < 4; ++c) {
            s16x8 b1 = *(const s16x8*)(Bp1 + kc * 2048 + c * 512);
            acc1[c] = __builtin_amdgcn_mfma_f32_16x16x32_bf16(a, b1, acc1[c], 0, 0, 0);
            s16x8 b2 = *(const s16x8*)(Bp2 + kc * 2048 + c * 512);
            acc2[c] = __builtin_amdgcn_mfma_f32_16x16x32_bf16(a, b2, acc2[c], 0, 0, 0);
        }
    }
    int col0 = lane & 15, rq = lane >> 4;
    unsigned short* Pb = PmQ + (size_t)b * cStride;
    unsigned short* Qb = Qh + (size_t)b * cStride;
#pragma unroll
    for (int r = 0; r < 4; ++r) {
        int grow = sg * 16 + rq * 4 + r;
#pragma unroll
        for (int c = 0; c < 4; ++c) {
            int col = n0 + c * 16 + col0;
            Pb[(size_t)grow * ldc + col] = f2bf(acc1[c][r] + bias[col]);
            Qb[(size_t)grow * ldc + col] = f2bf(acc2[c][r]);
        }
    }
}

// ---------------- fc2: bf16 out + bias + row scatter ----------------
template <int KC>
__global__ __launch_bounds__(256) void gemm_mfma_hb(const unsigned short* __restrict__ Af,
                                                    size_t aStride,
                                                    const unsigned short* __restrict__ Bf,
                                                    const float* __restrict__ bias,
                                                    unsigned short* __restrict__ C,
                                                    size_t cStride, int ldc,
                                                    const int* __restrict__ rowmap) {
    int b = blockIdx.z;
    int w = threadIdx.x >> 6, lane = threadIdx.x & 63;
    int sg = blockIdx.y * 4 + w;
    int n0 = blockIdx.x * 64;
    const unsigned short* Ap = Af + (size_t)b * aStride + ((size_t)sg * KC * 64 + lane) * 8;
    const unsigned short* Bp = Bf + ((size_t)blockIdx.x * KC * 256 + lane) * 8;
    f32x4 acc[4] = {};
#pragma unroll
    for (int kc = 0; kc < KC; ++kc) {
        s16x8 a = *(const s16x8*)(Ap + kc * 512);
#pragma unroll
        for (int c = 0; c < 4; ++c) {
            s16x8 bv = *(const s16x8*)(Bp + kc * 2048 + c * 512);
            acc[c] = __builtin_amdgcn_mfma_f32_16x16x32_bf16(a, bv, acc[c], 0, 0, 0);
        }
    }
    int col0 = lane & 15, rq = lane >> 4;
    unsigned short* Cb = C + (size_t)b * cStride;
#pragma unroll
    for (int r = 0; r < 4; ++r) {
        int grow = sg * 16 + rq * 4 + r;
        int orow = rowmap[(size_t)b * NN + grow];
#pragma unroll
        for (int c = 0; c < 4; ++c) {
            int col = n0 + c * 16 + col0;
            Cb[(size_t)orow * ldc + col] = f2bf(acc[c][r] + bias[col]);
        }
    }
}

// ---------------- xe = xs*rinv -> fp16 A-fragments; computes rinv + sqv in-kernel ----------------
__global__ __launch_bounds__(384) void xe_cvt_kernel(const float* __restrict__ xs,
                                                     const int* __restrict__ offk,
                                                     const int* __restrict__ cntk,
                                                     _Float16* __restrict__ xef,
                                                     float* __restrict__ sqv) {
    __shared__ float psum[16][25];
    __shared__ float rloc[16];
    int b = blockIdx.z, k = blockIdx.y, strip = blockIdx.x;
    int bk = b * NK + k;
    int base = offk[bk], L = cntk[bk];
    if (strip * 16 >= L) return;
    int kc = threadIdx.x >> 6, l = threadIdx.x & 63;
    int m = l & 15, q = l >> 4;
    int rl = strip * 16 + m;
    int row = base + (rl < L ? rl : L - 1);
    const float* src = xs + ((size_t)b * NN + row) * NC + kc * 32 + q * 8;
    float4 v0 = *(const float4*)src;
    float4 v1 = *(const float4*)(src + 4);
    float part = v0.x * v0.x + v0.y * v0.y + v0.z * v0.z + v0.w * v0.w + v1.x * v1.x +
                 v1.y * v1.y + v1.z * v1.z + v1.w * v1.w;
    psum[m][kc * 4 + q] = part;
    __syncthreads();
    if (threadIdx.x < 16) {
        float s = 0.0f;
#pragma unroll
        for (int i2 = 0; i2 < 24; ++i2) s += psum[threadIdx.x][i2];
        float nrm = fmaxf(sqrtf(s), 1e-12f);
        float ri = 1.0f / nrm;
        rloc[threadIdx.x] = ri;
        if (strip * 16 + (int)threadIdx.x < L)
            sqv[(size_t)b * NN + base + strip * 16 + threadIdx.x] = (s * ri) * ri;
    }
    __syncthreads();
    float rv = rloc[m];
    f16x8 pack;
    pack[0] = (_Float16)(v0.x * rv);
    pack[1] = (_Float16)(v0.y * rv);
    pack[2] = (_Float16)(v0.z * rv);
    pack[3] = (_Float16)(v0.w * rv);
    pack[4] = (_Float16)(v1.x * rv);
    pack[5] = (_Float16)(v1.y * rv);
    pack[6] = (_Float16)(v1.z * rv);
    pack[7] = (_Float16)(v1.w * rv);
    *(f16x8*)(xef + (size_t)bk * (20 * 6 * 512) + (((size_t)strip * 6 + kc) * 64 + l) * 8) =
        pack;
}

// ---------------- Gram -> d2 tiles via fp16 MFMA (stores only live rows/cols) ----------------
__global__ __launch_bounds__(256) void gram_kernel(const _Float16* __restrict__ xef,
                                                   const float* __restrict__ sqv,
                                                   const int* __restrict__ offk,
                                                   const int* __restrict__ cntk,
                                                   float* __restrict__ D) {
    int bk = blockIdx.z;
    int b = bk >> 4;
    int base = offk[bk], L = cntk[bk];
    int ti = blockIdx.x, tj = blockIdx.y;
    if (ti * 64 >= L || tj * 64 >= L) return;
    int w = threadIdx.x >> 6, lane = threadIdx.x & 63;
    const _Float16* Xf = xef + (size_t)bk * (20 * 6 * 512);
    const _Float16* Ap = Xf + (((size_t)(ti * 4 + w) * 6) * 64 + lane) * 8;
    f32x4 acc[4] = {};
#pragma unroll
    for (int kc = 0; kc < 6; ++kc) {
        f16x8 a = *(const f16x8*)(Ap + kc * 512);
#pragma unroll
        for (int js = 0; js < 4; ++js) {
            f16x8 bv = *(const f16x8*)(Xf + (((size_t)(tj * 4 + js) * 6 + kc) * 64 + lane) * 8);
            acc[js] = __builtin_amdgcn_mfma_f32_16x16x32_f16(a, bv, acc[js], 0, 0, 0);
        }
    }
    float* Dr = D + (size_t)bk * DSLOT;
    const float* Sb = sqv + (size_t)b * NN + base;
    int col0 = lane & 15, rq = lane >> 4;
#pragma unroll
    for (int r = 0; r < 4; ++r) {
        int i = ti * 64 + w * 16 + rq * 4 + r;
        if (i >= L) continue;
        float si = Sb[i];
#pragma unroll
        for (int js = 0; js < 4; ++js) {
            int j = tj * 64 + js * 16 + col0;
            if (j < L) Dr[(size_t)i * DSTRIDE + j] = si + Sb[j] - 2.0f * acc[js][r];
        }
    }
}

// ---------------- top-9 selection: one wave per row (sorted ids) ----------------
#define LEXLT(da, ca, db, cb) ((da) < (db) || ((da) == (db) && (ca) < (cb)))
__global__ __launch_bounds__(256) void select9_kernel(const float* __restrict__ D,
                                                      const int* __restrict__ lsv,
                                                      const int* __restrict__ offk,
                                                      const int* __restrict__ cntk,
                                                      int* __restrict__ nbr) {
    int b = blockIdx.y;
    int r = blockIdx.x * 4 + (threadIdx.x >> 6);
    int lane = threadIdx.x & 63;
    int k = lsv[(size_t)b * NN + r];
    int bk = b * NK + k;
    int base = offk[bk], L = cntk[bk];
    int Lc = L < LPMAX ? L : LPMAX;
    const float* Dr = D + (size_t)bk * DSLOT + (size_t)(r - base) * DSTRIDE;
    float d0, d1, d2, d3, d4;
    int c0, c1, c2, c3, c4;
    c0 = lane;
    c1 = lane + 64;
    c2 = lane + 128;
    c3 = lane + 192;
    c4 = lane + 256;
    d0 = c0 < Lc ? Dr[c0] : FLT_INF;
    d1 = c1 < Lc ? Dr[c1] : FLT_INF;
    d2 = c2 < Lc ? Dr[c2] : FLT_INF;
    d3 = c3 < Lc ? Dr[c3] : FLT_INF;
    d4 = c4 < Lc ? Dr[c4] : FLT_INF;
#define CS(da, ca, db, cb)                  \
    if (LEXLT(db, cb, da, ca)) {            \
        float t = da; da = db; db = t;      \
        int u = ca; ca = cb; cb = u;        \
    }
    CS(d0, c0, d1, c1) CS(d3, c3, d4, c4) CS(d2, c2, d4, c4) CS(d2, c2, d3, c3)
    CS(d1, c1, d4, c4) CS(d0, c0, d3, c3) CS(d0, c0, d2, c2) CS(d1, c1, d3, c3)
    CS(d1, c1, d2, c2)
#undef CS
    size_t row = (size_t)b * NN + r;
    for (int q = 0; q < KNB; ++q) {
        float bd = d0;
        int bc = c0;
#pragma unroll
        for (int m = 32; m; m >>= 1) {
            float od = __shfl_xor(bd, m, 64);
            int oc = __shfl_xor(bc, m, 64);
            if (LEXLT(od, oc, bd, bc)) {
                bd = od;
                bc = oc;
            }
        }
        if (lane == 0) nbr[row * KNB + q] = base + bc;
        if (d0 == bd && c0 == bc) {
            d0 = d1; c0 = c1;
            d1 = d2; c1 = c2;
            d2 = d3; c2 = c3;
            d3 = d4; c3 = c4;
            d4 = FLT_INF; c4 = 0x7fffffff;
        }
    }
}

// ---------------- merged centroids + cluster P/Q (one block per bk; centroid stays in LDS) ----------------
__global__ __launch_bounds__(768) void cenpq_kernel(const float* __restrict__ xs,
                                                    const int* __restrict__ offk,
                                                    const int* __restrict__ cntk,
                                                    const float* __restrict__ Wc,
                                                    const float* __restrict__ bc,
                                                    float* __restrict__ Pc,
                                                    float* __restrict__ Qc) {
    __shared__ float part[4][NC];
    __shared__ float ce[NC];
    __shared__ float pcs[NCOUT], qcs[NCOUT];
    int bk = blockIdx.x;
    int b = bk >> 4;
    int base = offk[bk], L = cntk[bk];
    int w = threadIdx.x / NC;  // 0..3 row partition
    int c = threadIdx.x % NC;
    const float* Xb = xs + ((size_t)b * NN + base) * NC + c;
    float s = 0.0f;
    for (int r = w; r < L; r += 4) s += Xb[(size_t)r * NC];
    part[w][c] = s;
    __syncthreads();
    if (threadIdx.x < NC) {
        int cc = threadIdx.x;
        float tot = part[0][cc] + part[1][cc] + part[2][cc] + part[3][cc];
        ce[cc] = tot / fmaxf((float)L, 1.0f);
    }
    __syncthreads();
    // P/Q: 768 threads = 2 halves x 384 outputs; each half sums 96 of the 192 c's
    int o = threadIdx.x % NCOUT, half = threadIdx.x / NCOUT;
    float pc = 0.0f, qc = 0.0f;
    int cs = half * 96, cend = cs + 96;
    for (int c2 = cs; c2 < cend; ++c2) {
        float cv = ce[c2];
        pc += cv * Wc[(size_t)c2 * NCOUT + o];
        qc += cv * Wc[(size_t)(NC + c2) * NCOUT + o];
    }
    if (half == 1) {
        pcs[o] = pc;
        qcs[o] = qc;
    }
    __syncthreads();
    if (half == 0) {
        Pc[(size_t)bk * NCOUT + o] = pc + pcs[o] + bc[o];
        Qc[(size_t)bk * NCOUT + o] = qc + qcs[o];
    }
}

// ---------------- cluster message max (valley trick, 128 blocks) ----------------
__global__ __launch_bounds__(384) void hcmax_kernel(const float* __restrict__ Pc,
                                                    const float* __restrict__ Qc,
                                                    float* __restrict__ hc) {
    int b = blockIdx.x >> 4, i = blockIdx.x & 15;
    int o = threadIdx.x;
    float pi = Pc[((size_t)b * NK + i) * NCOUT + o];
    float qi = Qc[((size_t)b * NK + i) * NCOUT + o];
    float pmq = pi - qi;
    float qmn = FLT_INF, qmx = -FLT_INF;
    for (int j = 0; j < NK; ++j) {
        float v = Qc[((size_t)b * NK + j) * NCOUT + o];
        qmn = fminf(qmn, v);
        qmx = fmaxf(qmx, v);
    }
    hc[((size_t)b * NK + i) * NCOUT + o] =
        fmaxf(gelu_t(pmq + qmn), gelu_t(pmq + qmx));
}

// ---------------- node max + cluster term -> hn bf16 A-fragments (sorted order) ----------------
// Rewritten: each thread owns 8 contiguous channels -> us8 vector loads for the 9-neighbor
// gather (was 54 scalar ushort loads/thread = VMEM-issue-bound), and the 8 outputs are
// exactly one us8 fragment store (no LDS staging, no __syncthreads).
__global__ __launch_bounds__(192) void hv_kernel(const unsigned short* __restrict__ PmQ,
                                                 const unsigned short* __restrict__ Qh,
                                                 const int* __restrict__ nbr,
                                                 const int* __restrict__ lsv,
                                                 const float* __restrict__ hc,
                                                 unsigned short* __restrict__ hnf) {
    int b = blockIdx.y;
    int t = threadIdx.x;           // 192 = 4 rows x 48 channel-chunks
    int rsub = t / 48, c = t % 48;
    int i = blockIdx.x * 4 + rsub;
    size_t row = (size_t)b * NN + i;
    int lab = lsv[row];
    int o0 = c * 8;
    int jn[KNB];
#pragma unroll
    for (int q = 0; q < KNB; ++q) jn[q] = nbr[row * KNB + q];
    const unsigned short* Qbb = Qh + (size_t)b * NN * NCOUT + o0;
    us8 pv = *(const us8*)(PmQ + row * NCOUT + o0);
    us8 q0 = *(const us8*)(Qbb + (size_t)jn[0] * NCOUT);
    float qmn[8], qmx[8];
#pragma unroll
    for (int e = 0; e < 8; ++e) {
        float v = bf2f(q0[e]);
        qmn[e] = v;
        qmx[e] = v;
    }
#pragma unroll
    for (int q = 1; q < KNB; ++q) {
        us8 qv = *(const us8*)(Qbb + (size_t)jn[q] * NCOUT);
#pragma unroll
        for (int e = 0; e < 8; ++e) {
            float v = bf2f(qv[e]);
            qmn[e] = fminf(qmn[e], v);
            qmx[e] = fmaxf(qmx[e], v);
        }
    }
    const float* hcr = hc + ((size_t)b * NK + lab) * NCOUT + o0;
    float4 h0 = *(const float4*)hcr;
    float4 h1 = *(const float4*)(hcr + 4);
    float hcv[8] = {h0.x, h0.y, h0.z, h0.w, h1.x, h1.y, h1.z, h1.w};
    unsigned short pack[8];
#pragma unroll
    for (int e = 0; e < 8; ++e) {
        float pmq = bf2f(pv[e]);
        float m = fmaxf(gelu_t(pmq + qmn[e]), gelu_t(pmq + qmx[e]));
        pack[e] = f2bf(m + hcv[e]);
    }
    int s = i >> 4, mm = i & 15;
    *(us8*)(hnf + (size_t)b * NN * NCOUT +
            (((size_t)s * 12 + (c >> 2)) * 64 + (c & 3) * 16 + mm) * 8) = *(const us8*)pack;
}

// ---------------- transpose (b,n,c)->(b,c,n) + residual (bf16 in, fp32 out) ----------------
__global__ void out_kernel(const unsigned short* __restrict__ T, const float* __restrict__ X,
                           float* __restrict__ Y) {
    __shared__ float t[32][33];
    int b = blockIdx.z;
    int n0 = blockIdx.y * 32, c0 = blockIdx.x * 32;
    int tx = threadIdx.x, ty = threadIdx.y;  // 32 x 8
#pragma unroll
    for (int q = 0; q < 4; ++q) {
        int n = n0 + ty + q * 8;
        t[ty + q * 8][tx] = bf2f(T[((size_t)b * NN + n) * NC + c0 + tx]);
    }
    __syncthreads();
#pragma unroll
    for (int q = 0; q < 4; ++q) {
        int c = c0 + ty + q * 8;
        size_t idx = ((size_t)b * NC + c) * NN + n0 + tx;
        Y[idx] = t[tx][ty + q * 8] + X[idx];
    }
}

extern "C" void kernel_launch(void* const* d_in, const int* in_sizes, int n_in, void* d_out,
                              int out_size, void* d_ws, size_t ws_size, hipStream_t stream) {
    const float* x = (const float*)d_in[0];
    const int* labels = (const int*)d_in[1];
    const float* cpe_w = (const float*)d_in[2];
    const float* cpe_b = (const float*)d_in[3];
    const float* fc1_w = (const float*)d_in[4];
    const float* fc1_b = (const float*)d_in[5];
    const float* nn_v_w = (const float*)d_in[6];
    const float* nn_v_b = (const float*)d_in[7];
    const float* nn_c_w = (const float*)d_in[8];
    const float* nn_c_b = (const float*)d_in[9];
    const float* fc2_w = (const float*)d_in[10];
    const float* fc2_b = (const float*)d_in[11];
    float* out = (float*)d_out;

    const size_t SZ_XS = (size_t)NB * NN * NC;
    const size_t SZ_P = (size_t)NB * NN * NCOUT;
    const size_t BN = (size_t)NB * NN;
    const size_t SZ_CEN = (size_t)NB * NK * NC;
    const size_t SZ_PC = (size_t)NB * NK * NCOUT;

    float* base = (float*)d_ws;
    float* xs = base;                 // sorted fc1 out (fp32); reused as bf16 out_t later
    float* xpeRegion = xs + SZ_XS;    // bf16 conv out (ushort)
    float* Pb = xpeRegion + SZ_XS;    // bf16 PmQ (sorted); Dbuf during knn
    float* Qb = Pb + SZ_P;            // bf16 Qh (sorted)
    float* rinv = Qb + SZ_P;          // unused slot (kept for layout stability)
    float* sqv = rinv + BN;
    float* cen = sqv + BN;            // unused now (centroid stays in LDS), layout kept
    float* Pc = cen + SZ_CEN;
    float* Qc = Pc + SZ_PC;
    float* hcv = Qc + SZ_PC;
    int* order = (int*)(hcv + SZ_PC);
    int* mapping = order + BN;
    int* lsv = mapping + BN;
    int* nbrv = lsv + BN;
    int* cntk = nbrv + BN * KNB;
    int* offk = cntk + NB * NK;
    unsigned short* xpe = (unsigned short*)xpeRegion;
    float* Dbuf = Pb;  // spans Pb..Qb, dead before the P/Q gemm
    unsigned short* PmQh = (unsigned short*)Pb;
    unsigned short* Qh = (unsigned short*)Qb;
    unsigned short* out_t = (unsigned short*)xs;  // xs fp32 dead after cen
    unsigned short* frag = (unsigned short*)(offk + NB * NK);
    unsigned short* xpeT_frag = frag;
    unsigned short* xs_frag = frag + SZ_XS;
    unsigned short* hn_frag = frag;  // alias, xpeT dead by hv time
    unsigned short* wf1 = frag + 2 * SZ_XS;
    unsigned short* wfpmq = wf1 + (size_t)NC * NC;    // (Wtop-Wbot) 192x384
    unsigned short* wfq = wfpmq + (size_t)NC * NCOUT; // Wbot 192x384
    unsigned short* wf2 = wfq + (size_t)NC * NCOUT;
    _Float16* xef = (_Float16*)(wf2 + (size_t)NCOUT * NC);

    // fused: conv | order | wcvt (independent; order's latency hides under conv)
    front_kernel<<<FRONT_CONV_BLOCKS + FRONT_ORDER_BLOCKS + FRONT_WCVT_BLOCKS, 256, 0, stream>>>(
        x, cpe_w, cpe_b, xpe, labels, order, mapping, lsv, cntk, offk, fc1_w, nn_v_w, fc2_w,
        wf1, wfpmq, wfq, wf2);
    tcvt_kernel<<<dim3(NN / 64, NC / 32, NB), 256, 0, stream>>>(xpe, xpeT_frag);
    // fc1: rows scattered to sorted order; xs fp32 + xs_frag bf16 (sorted)
    gemm_mfma<6><<<dim3(NC / 64, NN / 64, NB), 256, 0, stream>>>(
        xpeT_frag, SZ_XS / NB, wf1, fc1_b, xs, (size_t)NN * NC, NC, xs_frag, mapping);
    // xe fragments + rinv/sqv fused
    xe_cvt_kernel<<<dim3(LPMAX / 16, NK, NB), 384, 0, stream>>>(xs, offk, cntk, xef, sqv);
    gram_kernel<<<dim3(LPMAX / 64, LPMAX / 64, NB * NK), 256, 0, stream>>>(xef, sqv, offk,
                                                                           cntk, Dbuf);
    select9_kernel<<<dim3(NN / 4, NB), 256, 0, stream>>>(Dbuf, lsv, offk, cntk, nbrv);
    // merged: PmQ = xs@(Wtop-Wbot)+bias (bf16), Qh = xs@Wbot (bf16) — one A pass
    gemm_mfma_pq<6><<<dim3(NCOUT / 64, NN / 64, NB), 256, 0, stream>>>(
        xs_frag, SZ_XS / NB, wfpmq, wfq, nn_v_b, PmQh, Qh, (size_t)NN * NCOUT, NCOUT);
    // merged centroids + cluster P/Q (centroid kept in LDS)
    cenpq_kernel<<<NB * NK, 768, 0, stream>>>(xs, offk, cntk, nn_c_w, nn_c_b, Pc, Qc);
    hcmax_kernel<<<NB * NK, NCOUT, 0, stream>>>(Pc, Qc, hcv);
    hv_kernel<<<dim3(NN / 4, NB), 192, 0, stream>>>(PmQh, Qh, nbrv, lsv, hcv, hn_frag);
    // fc2: sorted rows -> bf16 out_t scattered to spatial order (xs region, fp32 xs dead)
    gemm_mfma_hb<12><<<dim3(NC / 64, NN / 64, NB), 256, 0, stream>>>(
        hn_frag, SZ_P / NB, wf2, fc2_b, out_t, (size_t)NN * NC, NC, order);
    out_kernel<<<dim3(NC / 32, NN / 32, NB), dim3(32, 8), 0, stream>>>(out_t, x, out);
}

// Round 2
// 283.973 us; speedup vs baseline: 1.1184x; 1.0462x over previous
//
#include <hip/hip_runtime.h>
#include <math.h>

#define NB 8
#define NC 192
#define NH 56
#define NW 56
#define NN 3136      // NH*NW
#define NK 16        // clusters
#define KNB 9        // neighbors
#define NCOUT 384    // 2*NC
#define LPMAX 320    // max padded cluster size (L~196±14, 320 is >8 sigma)
#define DSTRIDE 320
#define DSLOT (320 * 320)

#define FLT_INF __builtin_inff()

typedef short s16x8 __attribute__((ext_vector_type(8)));
typedef _Float16 f16x8 __attribute__((ext_vector_type(8)));
typedef float f32x4 __attribute__((ext_vector_type(4)));
typedef unsigned short us8 __attribute__((ext_vector_type(8)));
typedef unsigned short us4 __attribute__((ext_vector_type(4)));

// gelu(tanh approx) via exact sigmoid identity: 0.5*(1+tanh(u)) = 1/(1+exp(-2u)).
__device__ __forceinline__ float gelu_t(float x) {
    const float k0 = 0.7978845608028654f;
    float u = k0 * (x + 0.044715f * x * x * x);
    float sg = __builtin_amdgcn_rcpf(1.0f + __expf(-2.0f * u));
    return x * sg;
}

__device__ __forceinline__ unsigned short f2bf(float f) {
    unsigned u = __float_as_uint(f);
    u += 0x7fff + ((u >> 16) & 1);  // round-to-nearest-even
    return (unsigned short)(u >> 16);
}

__device__ __forceinline__ float bf2f(unsigned short h) {
    return __uint_as_float(((unsigned)h) << 16);
}

// ============================================================================
// XCD batch-affinity (T1, batch-per-XCD): MI355X dispatches linear workgroup
// ids round-robin across the 8 XCDs (lin%8). Every grid here has per-batch
// block counts exactly divisible, so remapping lin -> (xcd = lin%8 = batch,
// pos = lin/8) pins ALL of batch b's pipeline to XCD b. Each batch's
// intermediates (xpe 1.2MB, xs 2.4MB, xef 2MB, Qh+PmQ 4.8MB, hn 1.2MB) then
// live in that XCD's 4MiB L2 across producer->consumer kernel boundaries,
// turning hv's 173MB 16B-granule gather and all inter-kernel re-reads into
// L2 hits. Pure bijective index remap: bit-exact.
// ============================================================================

// ---------------- fused front kernel: conv (blocks 0..1535) | order | wcvt
#define FRONT_CONV_BLOCKS (NB * NC)            // 1536
#define FRONT_ORDER_BLOCKS (NB * NK)           // 128
#define FRONT_WCVT_BLOCKS 288                  // 6*12*4
__global__ __launch_bounds__(256) void front_kernel(
    const float* __restrict__ X, const float* __restrict__ W7, const float* __restrict__ bias,
    unsigned short* __restrict__ xpe,
    const int* __restrict__ labels, int* __restrict__ order, int* __restrict__ mapping,
    int* __restrict__ lsv, int* __restrict__ cntk, int* __restrict__ offk,
    const float* __restrict__ Wf1, const float* __restrict__ Wv, const float* __restrict__ Wf2,
    unsigned short* __restrict__ wf1, unsigned short* __restrict__ wfpmq,
    unsigned short* __restrict__ wfq, unsigned short* __restrict__ wf2) {
    __shared__ float tile[62 * 62];
    __shared__ float wl[49];
    int bid = blockIdx.x;
    int tid = threadIdx.x;
    if (bid < FRONT_CONV_BLOCKS) {
        // -------- depthwise 7x7 conv + bias + residual -> bf16 xpe --------
        // XCD remap: bc = (bid%8)*192 + bid/8  => batch = bid%8 = this XCD
        int bc = (bid & 7) * NC + (bid >> 3);
        int c = bc % NC;
        const float* Xp = X + (size_t)bc * NN;
        if (tid < 49) wl[tid] = W7[(size_t)c * 49 + tid];
        for (int idx = tid; idx < 62 * 62; idx += 256) {
            int ty = idx / 62, tx = idx % 62;
            int gy = ty - 3, gx = tx - 3;
            float v = 0.0f;
            if (gy >= 0 && gy < NH && gx >= 0 && gx < NW) v = Xp[gy * NW + gx];
            tile[idx] = v;
        }
        __syncthreads();
        float cb = bias[c];
        for (int g = tid; g < (NN / 4); g += 256) {
            int y = g / (NW / 4), x0 = (g % (NW / 4)) * 4;
            float a0 = 0.f, a1 = 0.f, a2 = 0.f, a3 = 0.f;
#pragma unroll
            for (int dy = 0; dy < 7; ++dy) {
                const float* tr = &tile[(y + dy) * 62 + x0];
#pragma unroll
                for (int dx = 0; dx < 7; ++dx) {
                    float wv = wl[dy * 7 + dx];
                    a0 += tr[dx] * wv;
                    a1 += tr[dx + 1] * wv;
                    a2 += tr[dx + 2] * wv;
                    a3 += tr[dx + 3] * wv;
                }
            }
            const float* rr = &tile[(y + 3) * 62 + x0 + 3];
            us4 o;
            o[0] = f2bf(a0 + cb + rr[0]);
            o[1] = f2bf(a1 + cb + rr[1]);
            o[2] = f2bf(a2 + cb + rr[2]);
            o[3] = f2bf(a3 + cb + rr[3]);
            *(us4*)(xpe + (size_t)bc * NN + y * NW + x0) = o;
        }
    } else if (bid < FRONT_CONV_BLOCKS + FRONT_ORDER_BLOCKS) {
        // -------- stable counting sort (wave 0 only) --------
        if (tid >= 64) return;
        int idx = bid - FRONT_CONV_BLOCKS;
        int b = idx >> 4;
        int k = idx & 15;
        int lane = tid;
        const int* lb = labels + (size_t)b * NN;
        int cntLess = 0, cntEq = 0;
        for (int n0 = 0; n0 < NN; n0 += 64) {
            int lab = lb[n0 + lane] & 15;
            cntLess += __popcll(__ballot(lab < k));
            cntEq += __popcll(__ballot(lab == k));
        }
        int base = cntLess;
        int run = 0;
        for (int n0 = 0; n0 < NN; n0 += 64) {
            int n = n0 + lane;
            int lab = lb[n] & 15;
            bool p = (lab == k);
            unsigned long long mask = __ballot(p);
            int rank = __popcll(mask & ((1ull << lane) - 1ull));
            if (p) {
                int pos = base + run + rank;
                order[b * NN + pos] = n;
                mapping[b * NN + n] = pos;
                lsv[b * NN + pos] = k;
            }
            run += __popcll(mask);
        }
        if (lane == 0) {
            offk[b * NK + k] = base;
            cntk[b * NK + k] = cntEq;
        }
    } else {
        // -------- weight -> B-fragment conversions --------
        int u = bid - (FRONT_CONV_BLOCKS + FRONT_ORDER_BLOCKS);
        int nt = u % 6, kc = (u / 6) % 12, z = u / 72;
        const float* W;
        unsigned short* Bf;
        int ldw, rowoff, KC, NT;
        bool diff = false;
        if (z == 0) { W = Wf1; Bf = wf1; ldw = NC; rowoff = 0; KC = 6; NT = 3; }
        else if (z == 1) { W = Wv; Bf = wfpmq; ldw = NCOUT; rowoff = 0; KC = 6; NT = 6; diff = true; }
        else if (z == 2) { W = Wv; Bf = wfq; ldw = NCOUT; rowoff = NC; KC = 6; NT = 6; }
        else { W = Wf2; Bf = wf2; ldw = NC; rowoff = 0; KC = 12; NT = 3; }
        if (nt >= NT || kc >= KC) return;
        int c = tid >> 6, l = tid & 63;
        int n = l & 15, q = l >> 4;
        int col = nt * 64 + c * 16 + n;
        int krow = rowoff + kc * 32 + q * 8;
        unsigned short pack[8];
#pragma unroll
        for (int j = 0; j < 8; ++j) {
            float v = W[(size_t)(krow + j) * ldw + col];
            if (diff) v -= W[(size_t)(NC + krow + j) * ldw + col];
            pack[j] = f2bf(v);
        }
        *(us8*)(Bf + ((((size_t)nt * KC + kc) * 4 + c) * 64 + l) * 8) = *(const us8*)pack;
    }
}

// ---------------- bf16 xpe [b][c][n] -> A-fragment for fc1 (pure repack) ----------------
__global__ __launch_bounds__(256) void tcvt_kernel(const unsigned short* __restrict__ xpe,
                                                   unsigned short* __restrict__ Af) {
    __shared__ unsigned short t[32][72];
    // grid (49,6,8) -> lin; XCD remap: b = lin%8, pos = lin/8 in [0,294)=6x49
    int lin = ((int)blockIdx.z * 6 + blockIdx.y) * 49 + blockIdx.x;
    int b = lin & 7, pos = lin >> 3;
    int kc = pos / 49, nx = pos % 49;
    int n0 = nx * 64;
    int tid = threadIdx.x;
    int cl = tid >> 3, nl = (tid & 7) * 8;
    const unsigned short* src = xpe + ((size_t)b * NC + kc * 32 + cl) * NN + n0 + nl;
    *(us8*)&t[cl][nl] = *(const us8*)src;
    __syncthreads();
    int w = tid >> 6, l = tid & 63;
    int m = l & 15, q = l >> 4;
    int nloc = w * 16 + m;
    unsigned short pack[8];
#pragma unroll
    for (int j = 0; j < 8; ++j) pack[j] = t[q * 8 + j][nloc];
    int sg = nx * 4 + w;
    *(us8*)(Af + (size_t)b * NN * NC + (((size_t)sg * 6 + kc) * 64 + l) * 8) =
        *(const us8*)pack;
}

// ---------------- LDS-free MFMA GEMM: fragment-streaming, fp32 out (+opt scatter/frag) ----------------
template <int KC>
__global__ __launch_bounds__(256) void gemm_mfma(const unsigned short* __restrict__ Af,
                                                 size_t aStride,
                                                 const unsigned short* __restrict__ Bf,
                                                 const float* __restrict__ bias,
                                                 float* __restrict__ C, size_t cStride,
                                                 int ldc, unsigned short* __restrict__ Cfrag,
                                                 const int* __restrict__ rowmap) {
    // grid (NX,49,8); XCD remap: b = lin%8, pos = lin/8; x = pos%NX, y = pos/NX
    int NX = gridDim.x;
    int lin = ((int)blockIdx.z * 49 + blockIdx.y) * NX + blockIdx.x;
    int b = lin & 7, pos = lin >> 3;
    int bx = pos % NX, by = pos / NX;
    int w = threadIdx.x >> 6, lane = threadIdx.x & 63;
    int sg = by * 4 + w;
    int n0 = bx * 64;
    const unsigned short* Ap = Af + (size_t)b * aStride + ((size_t)sg * KC * 64 + lane) * 8;
    const unsigned short* Bp = Bf + ((size_t)bx * KC * 256 + lane) * 8;
    f32x4 acc[4] = {};
#pragma unroll
    for (int kc = 0; kc < KC; ++kc) {
        s16x8 a = *(const s16x8*)(Ap + kc * 512);
#pragma unroll
        for (int c = 0; c < 4; ++c) {
            s16x8 bv = *(const s16x8*)(Bp + kc * 2048 + c * 512);
            acc[c] = __builtin_amdgcn_mfma_f32_16x16x32_bf16(a, bv, acc[c], 0, 0, 0);
        }
    }
    int col0 = lane & 15, rq = lane >> 4;
    float* Cb = C + (size_t)b * cStride;
    int kcd = ldc >> 5;
#pragma unroll
    for (int r = 0; r < 4; ++r) {
        int grow = sg * 16 + rq * 4 + r;
        int orow = rowmap ? rowmap[(size_t)b * NN + grow] : grow;
#pragma unroll
        for (int c = 0; c < 4; ++c) {
            int col = n0 + c * 16 + col0;
            float v = acc[c][r];
            if (bias) v += bias[col];
            Cb[(size_t)orow * ldc + col] = v;
            if (Cfrag) {
                int s2 = orow >> 4, m2 = orow & 15;
                int kc2 = col >> 5, q2 = (col >> 3) & 3, j2 = col & 7;
                Cfrag[(size_t)b * cStride +
                      (((size_t)s2 * kcd + kc2) * 64 + q2 * 16 + m2) * 8 + j2] = f2bf(v);
            }
        }
    }
}

// ---------------- merged P/Q GEMM: one A pass, two bf16 outputs ----------------
template <int KC>
__global__ __launch_bounds__(256) void gemm_mfma_pq(const unsigned short* __restrict__ Af,
                                                    size_t aStride,
                                                    const unsigned short* __restrict__ B1,
                                                    const unsigned short* __restrict__ B2,
                                                    const float* __restrict__ bias,
                                                    unsigned short* __restrict__ PmQ,
                                                    unsigned short* __restrict__ Qh,
                                                    size_t cStride, int ldc) {
    // grid (6,49,8); XCD remap as gemm_mfma
    int lin = ((int)blockIdx.z * 49 + blockIdx.y) * 6 + blockIdx.x;
    int b = lin & 7, pos = lin >> 3;
    int bx = pos % 6, by = pos / 6;
    int w = threadIdx.x >> 6, lane = threadIdx.x & 63;
    int sg = by * 4 + w;
    int n0 = bx * 64;
    const unsigned short* Ap = Af + (size_t)b * aStride + ((size_t)sg * KC * 64 + lane) * 8;
    const unsigned short* Bp1 = B1 + ((size_t)bx * KC * 256 + lane) * 8;
    const unsigned short* Bp2 = B2 + ((size_t)bx * KC * 256 + lane) * 8;
    f32x4 acc1[4] = {};
    f32x4 acc2[4] = {};
#pragma unroll
    for (int kc = 0; kc < KC; ++kc) {
        s16x8 a = *(const s16x8*)(Ap + kc * 512);
#pragma unroll
        for (int c = 0; c < 4; ++c) {
            s16x8 b1 = *(const s16x8*)(Bp1 + kc * 2048 + c * 512);
            acc1[c] = __builtin_amdgcn_mfma_f32_16x16x32_bf16(a, b1, acc1[c], 0, 0, 0);
            s16x8 b2 = *(const s16x8*)(Bp2 + kc * 2048 + c * 512);
            acc2[c] = __builtin_amdgcn_mfma_f32_16x16x32_bf16(a, b2, acc2[c], 0, 0, 0);
        }
    }
    int col0 = lane & 15, rq = lane >> 4;
    unsigned short* Pb = PmQ + (size_t)b * cStride;
    unsigned short* Qb = Qh + (size_t)b * cStride;
#pragma unroll
    for (int r = 0; r < 4; ++r) {
        int grow = sg * 16 + rq * 4 + r;
#pragma unroll
        for (int c = 0; c < 4; ++c) {
            int col = n0 + c * 16 + col0;
            Pb[(size_t)grow * ldc + col] = f2bf(acc1[c][r] + bias[col]);
            Qb[(size_t)grow * ldc + col] = f2bf(acc2[c][r]);
        }
    }
}

// ---------------- fc2: bf16 out + bias, CONTIGUOUS sorted rows (de-scattered) ----------------
// The order->spatial permutation moved into out_kernel's row gather: store side is
// now dense 16x64 tiles (full cache lines), all within this XCD's L2 slice.
template <int KC>
__global__ __launch_bounds__(256) void gemm_mfma_hb(const unsigned short* __restrict__ Af,
                                                    size_t aStride,
                                                    const unsigned short* __restrict__ Bf,
                                                    const float* __restrict__ bias,
                                                    unsigned short* __restrict__ C,
                                                    size_t cStride, int ldc) {
    // grid (3,49,8); XCD remap as gemm_mfma
    int lin = ((int)blockIdx.z * 49 + blockIdx.y) * 3 + blockIdx.x;
    int b = lin & 7, pos = lin >> 3;
    int bx = pos % 3, by = pos / 3;
    int w = threadIdx.x >> 6, lane = threadIdx.x & 63;
    int sg = by * 4 + w;
    int n0 = bx * 64;
    const unsigned short* Ap = Af + (size_t)b * aStride + ((size_t)sg * KC * 64 + lane) * 8;
    const unsigned short* Bp = Bf + ((size_t)bx * KC * 256 + lane) * 8;
    f32x4 acc[4] = {};
#pragma unroll
    for (int kc = 0; kc < KC; ++kc) {
        s16x8 a = *(const s16x8*)(Ap + kc * 512);
#pragma unroll
        for (int c = 0; c < 4; ++c) {
            s16x8 bv = *(const s16x8*)(Bp + kc * 2048 + c * 512);
            acc[c] = __builtin_amdgcn_mfma_f32_16x16x32_bf16(a, bv, acc[c], 0, 0, 0);
        }
    }
    int col0 = lane & 15, rq = lane >> 4;
    unsigned short* Cb = C + (size_t)b * cStride;
#pragma unroll
    for (int r = 0; r < 4; ++r) {
        int grow = sg * 16 + rq * 4 + r;
#pragma unroll
        for (int c = 0; c < 4; ++c) {
            int col = n0 + c * 16 + col0;
            Cb[(size_t)grow * ldc + col] = f2bf(acc[c][r] + bias[col]);
        }
    }
}

// ---------------- xe = xs*rinv -> fp16 A-fragments; computes rinv + sqv in-kernel ----------------
__global__ __launch_bounds__(384) void xe_cvt_kernel(const float* __restrict__ xs,
                                                     const int* __restrict__ offk,
                                                     const int* __restrict__ cntk,
                                                     _Float16* __restrict__ xef,
                                                     float* __restrict__ sqv) {
    __shared__ float psum[16][25];
    __shared__ float rloc[16];
    // grid (20,16,8); XCD remap: b = lin%8, pos=lin/8 in [0,320)=16x20
    int lin = ((int)blockIdx.z * 16 + blockIdx.y) * 20 + blockIdx.x;
    int b = lin & 7, pos = lin >> 3;
    int k = pos / 20, strip = pos % 20;
    int bk = b * NK + k;
    int base = offk[bk], L = cntk[bk];
    if (strip * 16 >= L) return;
    int kc = threadIdx.x >> 6, l = threadIdx.x & 63;
    int m = l & 15, q = l >> 4;
    int rl = strip * 16 + m;
    int row = base + (rl < L ? rl : L - 1);
    const float* src = xs + ((size_t)b * NN + row) * NC + kc * 32 + q * 8;
    float4 v0 = *(const float4*)src;
    float4 v1 = *(const float4*)(src + 4);
    float part = v0.x * v0.x + v0.y * v0.y + v0.z * v0.z + v0.w * v0.w + v1.x * v1.x +
                 v1.y * v1.y + v1.z * v1.z + v1.w * v1.w;
    psum[m][kc * 4 + q] = part;
    __syncthreads();
    if (threadIdx.x < 16) {
        float s = 0.0f;
#pragma unroll
        for (int i2 = 0; i2 < 24; ++i2) s += psum[threadIdx.x][i2];
        float nrm = fmaxf(sqrtf(s), 1e-12f);
        float ri = 1.0f / nrm;
        rloc[threadIdx.x] = ri;
        if (strip * 16 + (int)threadIdx.x < L)
            sqv[(size_t)b * NN + base + strip * 16 + threadIdx.x] = (s * ri) * ri;
    }
    __syncthreads();
    float rv = rloc[m];
    f16x8 pack;
    pack[0] = (_Float16)(v0.x * rv);
    pack[1] = (_Float16)(v0.y * rv);
    pack[2] = (_Float16)(v0.z * rv);
    pack[3] = (_Float16)(v0.w * rv);
    pack[4] = (_Float16)(v1.x * rv);
    pack[5] = (_Float16)(v1.y * rv);
    pack[6] = (_Float16)(v1.z * rv);
    pack[7] = (_Float16)(v1.w * rv);
    *(f16x8*)(xef + (size_t)bk * (20 * 6 * 512) + (((size_t)strip * 6 + kc) * 64 + l) * 8) =
        pack;
}

// ---------------- Gram -> d2 tiles via fp16 MFMA (stores only live rows/cols) ----------------
__global__ __launch_bounds__(256) void gram_kernel(const _Float16* __restrict__ xef,
                                                   const float* __restrict__ sqv,
                                                   const int* __restrict__ offk,
                                                   const int* __restrict__ cntk,
                                                   float* __restrict__ D) {
    // grid (5,5,128); XCD remap: b = lin%8, pos=lin/8 in [0,400)=16x5x5
    int lin = ((int)blockIdx.z * 5 + blockIdx.y) * 5 + blockIdx.x;
    int b = lin & 7, pos = lin >> 3;
    int k = pos / 25, rr = pos % 25;
    int tj = rr / 5, ti = rr % 5;
    int bk = b * NK + k;
    int base = offk[bk], L = cntk[bk];
    if (ti * 64 >= L || tj * 64 >= L) return;
    int w = threadIdx.x >> 6, lane = threadIdx.x & 63;
    const _Float16* Xf = xef + (size_t)bk * (20 * 6 * 512);
    const _Float16* Ap = Xf + (((size_t)(ti * 4 + w) * 6) * 64 + lane) * 8;
    f32x4 acc[4] = {};
#pragma unroll
    for (int kc = 0; kc < 6; ++kc) {
        f16x8 a = *(const f16x8*)(Ap + kc * 512);
#pragma unroll
        for (int js = 0; js < 4; ++js) {
            f16x8 bv = *(const f16x8*)(Xf + (((size_t)(tj * 4 + js) * 6 + kc) * 64 + lane) * 8);
            acc[js] = __builtin_amdgcn_mfma_f32_16x16x32_f16(a, bv, acc[js], 0, 0, 0);
        }
    }
    float* Dr = D + (size_t)bk * DSLOT;
    const float* Sb = sqv + (size_t)b * NN + base;
    int col0 = lane & 15, rq = lane >> 4;
#pragma unroll
    for (int r = 0; r < 4; ++r) {
        int i = ti * 64 + w * 16 + rq * 4 + r;
        if (i >= L) continue;
        float si = Sb[i];
#pragma unroll
        for (int js = 0; js < 4; ++js) {
            int j = tj * 64 + js * 16 + col0;
            if (j < L) Dr[(size_t)i * DSTRIDE + j] = si + Sb[j] - 2.0f * acc[js][r];
        }
    }
}

// ---------------- top-9 selection: one wave per row (sorted ids) ----------------
#define LEXLT(da, ca, db, cb) ((da) < (db) || ((da) == (db) && (ca) < (cb)))
__global__ __launch_bounds__(256) void select9_kernel(const float* __restrict__ D,
                                                      const int* __restrict__ lsv,
                                                      const int* __restrict__ offk,
                                                      const int* __restrict__ cntk,
                                                      int* __restrict__ nbr) {
    // grid (784,8); XCD remap: b = lin%8, quad = lin/8 -> reads D[b] from gram's XCD
    int lin = (int)blockIdx.y * 784 + blockIdx.x;
    int b = lin & 7, quad = lin >> 3;
    int r = quad * 4 + (threadIdx.x >> 6);
    int lane = threadIdx.x & 63;
    int k = lsv[(size_t)b * NN + r];
    int bk = b * NK + k;
    int base = offk[bk], L = cntk[bk];
    int Lc = L < LPMAX ? L : LPMAX;
    const float* Dr = D + (size_t)bk * DSLOT + (size_t)(r - base) * DSTRIDE;
    float d0, d1, d2, d3, d4;
    int c0, c1, c2, c3, c4;
    c0 = lane;
    c1 = lane + 64;
    c2 = lane + 128;
    c3 = lane + 192;
    c4 = lane + 256;
    d0 = c0 < Lc ? Dr[c0] : FLT_INF;
    d1 = c1 < Lc ? Dr[c1] : FLT_INF;
    d2 = c2 < Lc ? Dr[c2] : FLT_INF;
    d3 = c3 < Lc ? Dr[c3] : FLT_INF;
    d4 = c4 < Lc ? Dr[c4] : FLT_INF;
#define CS(da, ca, db, cb)                  \
    if (LEXLT(db, cb, da, ca)) {            \
        float t = da; da = db; db = t;      \
        int u = ca; ca = cb; cb = u;        \
    }
    CS(d0, c0, d1, c1) CS(d3, c3, d4, c4) CS(d2, c2, d4, c4) CS(d2, c2, d3, c3)
    CS(d1, c1, d4, c4) CS(d0, c0, d3, c3) CS(d0, c0, d2, c2) CS(d1, c1, d3, c3)
    CS(d1, c1, d2, c2)
#undef CS
    size_t row = (size_t)b * NN + r;
    for (int q = 0; q < KNB; ++q) {
        float bd = d0;
        int bc = c0;
#pragma unroll
        for (int m = 32; m; m >>= 1) {
            float od = __shfl_xor(bd, m, 64);
            int oc = __shfl_xor(bc, m, 64);
            if (LEXLT(od, oc, bd, bc)) {
                bd = od;
                bc = oc;
            }
        }
        if (lane == 0) nbr[row * KNB + q] = base + bc;
        if (d0 == bd && c0 == bc) {
            d0 = d1; c0 = c1;
            d1 = d2; c1 = c2;
            d2 = d3; c2 = c3;
            d3 = d4; c3 = c4;
            d4 = FLT_INF; c4 = 0x7fffffff;
        }
    }
}

// ---------------- merged centroids + cluster P/Q (one block per bk) ----------------
__global__ __launch_bounds__(768) void cenpq_kernel(const float* __restrict__ xs,
                                                    const int* __restrict__ offk,
                                                    const int* __restrict__ cntk,
                                                    const float* __restrict__ Wc,
                                                    const float* __restrict__ bc,
                                                    float* __restrict__ Pc,
                                                    float* __restrict__ Qc) {
    __shared__ float part[4][NC];
    __shared__ float ce[NC];
    __shared__ float pcs[NCOUT], qcs[NCOUT];
    // 128 blocks; XCD remap: bk = (bid%8)*16 + bid/8 -> b = bid%8
    int bk = ((int)blockIdx.x & 7) * NK + ((int)blockIdx.x >> 3);
    int b = bk >> 4;
    int base = offk[bk], L = cntk[bk];
    int w = threadIdx.x / NC;  // 0..3 row partition
    int c = threadIdx.x % NC;
    const float* Xb = xs + ((size_t)b * NN + base) * NC + c;
    float s = 0.0f;
    for (int r = w; r < L; r += 4) s += Xb[(size_t)r * NC];
    part[w][c] = s;
    __syncthreads();
    if (threadIdx.x < NC) {
        int cc = threadIdx.x;
        float tot = part[0][cc] + part[1][cc] + part[2][cc] + part[3][cc];
        ce[cc] = tot / fmaxf((float)L, 1.0f);
    }
    __syncthreads();
    int o = threadIdx.x % NCOUT, half = threadIdx.x / NCOUT;
    float pc = 0.0f, qc = 0.0f;
    int cs = half * 96, cend = cs + 96;
    for (int c2 = cs; c2 < cend; ++c2) {
        float cv = ce[c2];
        pc += cv * Wc[(size_t)c2 * NCOUT + o];
        qc += cv * Wc[(size_t)(NC + c2) * NCOUT + o];
    }
    if (half == 1) {
        pcs[o] = pc;
        qcs[o] = qc;
    }
    __syncthreads();
    if (half == 0) {
        Pc[(size_t)bk * NCOUT + o] = pc + pcs[o] + bc[o];
        Qc[(size_t)bk * NCOUT + o] = qc + qcs[o];
    }
}

// ---------------- cluster message max (valley trick, 128 blocks) ----------------
__global__ __launch_bounds__(384) void hcmax_kernel(const float* __restrict__ Pc,
                                                    const float* __restrict__ Qc,
                                                    float* __restrict__ hc) {
    // XCD remap consistent with cenpq: b = bid%8
    int bk = ((int)blockIdx.x & 7) * NK + ((int)blockIdx.x >> 3);
    int b = bk >> 4, i = bk & 15;
    int o = threadIdx.x;
    float pi = Pc[((size_t)b * NK + i) * NCOUT + o];
    float qi = Qc[((size_t)b * NK + i) * NCOUT + o];
    float pmq = pi - qi;
    float qmn = FLT_INF, qmx = -FLT_INF;
    for (int j = 0; j < NK; ++j) {
        float v = Qc[((size_t)b * NK + j) * NCOUT + o];
        qmn = fminf(qmn, v);
        qmx = fmaxf(qmx, v);
    }
    hc[((size_t)b * NK + i) * NCOUT + o] =
        fmaxf(gelu_t(pmq + qmn), gelu_t(pmq + qmx));
}

// ---------------- node max + cluster term -> hn bf16 A-fragments (sorted order) ----------------
__global__ __launch_bounds__(192) void hv_kernel(const unsigned short* __restrict__ PmQ,
                                                 const unsigned short* __restrict__ Qh,
                                                 const int* __restrict__ nbr,
                                                 const int* __restrict__ lsv,
                                                 const float* __restrict__ hc,
                                                 unsigned short* __restrict__ hnf) {
    // grid (784,8); XCD remap: b = lin%8 -> the 9-neighbor gather into Qh[b]
    // (2.4MB, written by pq on this same XCD) is L2-local.
    int lin = (int)blockIdx.y * 784 + blockIdx.x;
    int b = lin & 7, quad = lin >> 3;
    int t = threadIdx.x;           // 192 = 4 rows x 48 channel-chunks
    int rsub = t / 48, c = t % 48;
    int i = quad * 4 + rsub;
    size_t row = (size_t)b * NN + i;
    int lab = lsv[row];
    int o0 = c * 8;
    int jn[KNB];
#pragma unroll
    for (int q = 0; q < KNB; ++q) jn[q] = nbr[row * KNB + q];
    const unsigned short* Qbb = Qh + (size_t)b * NN * NCOUT + o0;
    us8 pv = *(const us8*)(PmQ + row * NCOUT + o0);
    us8 q0 = *(const us8*)(Qbb + (size_t)jn[0] * NCOUT);
    float qmn[8], qmx[8];
#pragma unroll
    for (int e = 0; e < 8; ++e) {
        float v = bf2f(q0[e]);
        qmn[e] = v;
        qmx[e] = v;
    }
#pragma unroll
    for (int q = 1; q < KNB; ++q) {
        us8 qv = *(const us8*)(Qbb + (size_t)jn[q] * NCOUT);
#pragma unroll
        for (int e = 0; e < 8; ++e) {
            float v = bf2f(qv[e]);
            qmn[e] = fminf(qmn[e], v);
            qmx[e] = fmaxf(qmx[e], v);
        }
    }
    const float* hcr = hc + ((size_t)b * NK + lab) * NCOUT + o0;
    float4 h0 = *(const float4*)hcr;
    float4 h1 = *(const float4*)(hcr + 4);
    float hcv[8] = {h0.x, h0.y, h0.z, h0.w, h1.x, h1.y, h1.z, h1.w};
    unsigned short pack[8];
#pragma unroll
    for (int e = 0; e < 8; ++e) {
        float pmq = bf2f(pv[e]);
        float m = fmaxf(gelu_t(pmq + qmn[e]), gelu_t(pmq + qmx[e]));
        pack[e] = f2bf(m + hcv[e]);
    }
    int s = i >> 4, mm = i & 15;
    *(us8*)(hnf + (size_t)b * NN * NCOUT +
            (((size_t)s * 12 + (c >> 2)) * 64 + (c & 3) * 16 + mm) * 8) = *(const us8*)pack;
}

// ---------------- transpose (b,n,c)->(b,c,n) + residual; row gather via mapping ----------------
__global__ void out_kernel(const unsigned short* __restrict__ T, const float* __restrict__ X,
                           const int* __restrict__ mapping, float* __restrict__ Y) {
    __shared__ float t[32][33];
    // grid (6,98,8); XCD remap: b = lin%8, pos = lin/8 in [0,588)=98x6
    int lin = ((int)blockIdx.z * 98 + blockIdx.y) * 6 + blockIdx.x;
    int b = lin & 7, pos = lin >> 3;
    int c0 = (pos % 6) * 32, n0 = (pos / 6) * 32;
    int tx = threadIdx.x, ty = threadIdx.y;  // 32 x 8
#pragma unroll
    for (int q = 0; q < 4; ++q) {
        int n = n0 + ty + q * 8;
        int srow = mapping[(size_t)b * NN + n];  // sorted row for spatial n (64B row gather)
        t[ty + q * 8][tx] = bf2f(T[((size_t)b * NN + srow) * NC + c0 + tx]);
    }
    __syncthreads();
#pragma unroll
    for (int q = 0; q < 4; ++q) {
        int c = c0 + ty + q * 8;
        size_t idx = ((size_t)b * NC + c) * NN + n0 + tx;
        Y[idx] = t[tx][ty + q * 8] + X[idx];
    }
}

extern "C" void kernel_launch(void* const* d_in, const int* in_sizes, int n_in, void* d_out,
                              int out_size, void* d_ws, size_t ws_size, hipStream_t stream) {
    const float* x = (const float*)d_in[0];
    const int* labels = (const int*)d_in[1];
    const float* cpe_w = (const float*)d_in[2];
    const float* cpe_b = (const float*)d_in[3];
    const float* fc1_w = (const float*)d_in[4];
    const float* fc1_b = (const float*)d_in[5];
    const float* nn_v_w = (const float*)d_in[6];
    const float* nn_v_b = (const float*)d_in[7];
    const float* nn_c_w = (const float*)d_in[8];
    const float* nn_c_b = (const float*)d_in[9];
    const float* fc2_w = (const float*)d_in[10];
    const float* fc2_b = (const float*)d_in[11];
    float* out = (float*)d_out;

    const size_t SZ_XS = (size_t)NB * NN * NC;
    const size_t SZ_P = (size_t)NB * NN * NCOUT;
    const size_t BN = (size_t)NB * NN;
    const size_t SZ_CEN = (size_t)NB * NK * NC;
    const size_t SZ_PC = (size_t)NB * NK * NCOUT;

    float* base = (float*)d_ws;
    float* xs = base;                 // sorted fc1 out (fp32); reused as bf16 out_t later
    float* xpeRegion = xs + SZ_XS;    // bf16 conv out (ushort)
    float* Pb = xpeRegion + SZ_XS;    // bf16 PmQ (sorted); Dbuf during knn
    float* Qb = Pb + SZ_P;            // bf16 Qh (sorted)
    float* rinv = Qb + SZ_P;          // unused slot (kept for layout stability)
    float* sqv = rinv + BN;
    float* cen = sqv + BN;            // unused (centroid in LDS), layout kept
    float* Pc = cen + SZ_CEN;
    float* Qc = Pc + SZ_PC;
    float* hcv = Qc + SZ_PC;
    int* order = (int*)(hcv + SZ_PC);
    int* mapping = order + BN;
    int* lsv = mapping + BN;
    int* nbrv = lsv + BN;
    int* cntk = nbrv + BN * KNB;
    int* offk = cntk + NB * NK;
    unsigned short* xpe = (unsigned short*)xpeRegion;
    float* Dbuf = Pb;  // spans Pb..Qb, dead before the P/Q gemm
    unsigned short* PmQh = (unsigned short*)Pb;
    unsigned short* Qh = (unsigned short*)Qb;
    unsigned short* out_t = (unsigned short*)xs;  // xs fp32 dead after cenpq
    unsigned short* frag = (unsigned short*)(offk + NB * NK);
    unsigned short* xpeT_frag = frag;
    unsigned short* xs_frag = frag + SZ_XS;
    unsigned short* hn_frag = frag;  // alias, xpeT dead by hv time
    unsigned short* wf1 = frag + 2 * SZ_XS;
    unsigned short* wfpmq = wf1 + (size_t)NC * NC;    // (Wtop-Wbot) 192x384
    unsigned short* wfq = wfpmq + (size_t)NC * NCOUT; // Wbot 192x384
    unsigned short* wf2 = wfq + (size_t)NC * NCOUT;
    _Float16* xef = (_Float16*)(wf2 + (size_t)NCOUT * NC);

    // fused: conv | order | wcvt (independent; order's latency hides under conv)
    front_kernel<<<FRONT_CONV_BLOCKS + FRONT_ORDER_BLOCKS + FRONT_WCVT_BLOCKS, 256, 0, stream>>>(
        x, cpe_w, cpe_b, xpe, labels, order, mapping, lsv, cntk, offk, fc1_w, nn_v_w, fc2_w,
        wf1, wfpmq, wfq, wf2);
    tcvt_kernel<<<dim3(NN / 64, NC / 32, NB), 256, 0, stream>>>(xpe, xpeT_frag);
    // fc1: rows scattered to sorted order; xs fp32 + xs_frag bf16 (sorted)
    gemm_mfma<6><<<dim3(NC / 64, NN / 64, NB), 256, 0, stream>>>(
        xpeT_frag, SZ_XS / NB, wf1, fc1_b, xs, (size_t)NN * NC, NC, xs_frag, mapping);
    // xe fragments + rinv/sqv fused
    xe_cvt_kernel<<<dim3(LPMAX / 16, NK, NB), 384, 0, stream>>>(xs, offk, cntk, xef, sqv);
    gram_kernel<<<dim3(LPMAX / 64, LPMAX / 64, NB * NK), 256, 0, stream>>>(xef, sqv, offk,
                                                                           cntk, Dbuf);
    select9_kernel<<<dim3(NN / 4, NB), 256, 0, stream>>>(Dbuf, lsv, offk, cntk, nbrv);
    // merged: PmQ = xs@(Wtop-Wbot)+bias (bf16), Qh = xs@Wbot (bf16) — one A pass
    gemm_mfma_pq<6><<<dim3(NCOUT / 64, NN / 64, NB), 256, 0, stream>>>(
        xs_frag, SZ_XS / NB, wfpmq, wfq, nn_v_b, PmQh, Qh, (size_t)NN * NCOUT, NCOUT);
    // merged centroids + cluster P/Q (centroid kept in LDS)
    cenpq_kernel<<<NB * NK, 768, 0, stream>>>(xs, offk, cntk, nn_c_w, nn_c_b, Pc, Qc);
    hcmax_kernel<<<NB * NK, NCOUT, 0, stream>>>(Pc, Qc, hcv);
    hv_kernel<<<dim3(NN / 4, NB), 192, 0, stream>>>(PmQh, Qh, nbrv, lsv, hcv, hn_frag);
    // fc2: contiguous sorted rows (permutation moved to out_kernel's gather)
    gemm_mfma_hb<12><<<dim3(NC / 64, NN / 64, NB), 256, 0, stream>>>(
        hn_frag, SZ_P / NB, wf2, fc2_b, out_t, (size_t)NN * NC, NC);
    out_kernel<<<dim3(NC / 32, NN / 32, NB), dim3(32, 8), 0, stream>>>(out_t, x, mapping, out);
}